// Round 4
// baseline (115.316 us; speedup 1.0000x reference)
//
#include <hip/hip_runtime.h>
#include <math.h>

#define NC 10
#define NP 128
#define ND 512
#define GAMMA  0.1f
#define BCONST 10.0f
#define TAO    1.0f
#define LAMBDA 0.1f
#define THR2   1600.0f     // THRESHOLD^2 (compare d2 instead of sqrt(d2))
#define FEPS   1e-6f
#define NLDS   12          // fallback: proto slots 1..NLDS in LDS; slot 0 in regs; rest global
#define CH     32          // speculation chunk size
#define MAXCH  256         // max chunks per class (covers all-8192-in-one-class)
#define IMAX   0x7FFFFFFF

__device__ __forceinline__ float allred64(float v) {
#pragma unroll
  for (int m = 1; m < 64; m <<= 1) v += __shfl_xor(v, m, 64);
  return v;
}

// ---------------------------------------------------------------------------
// A: stable per-class compaction -> order list + class bases/counts.
// One block, 256 threads. Also resets flags / fail_pos / nproto and d_out
// (graph-replay determinism; no in-graph memset nodes).
// ---------------------------------------------------------------------------
__global__ __launch_bounds__(256)
void ord_kernel(const int* __restrict__ labels, int B,
                int* __restrict__ order, int* __restrict__ cls_base,
                int* __restrict__ cls_cnt, int* __restrict__ fail_pos,
                int* __restrict__ flags, int* __restrict__ nproto_g,
                float* __restrict__ out)
{
  __shared__ int lab[8192];
  __shared__ int cnts[256][NC + 1];     // +1 pad (stride 11, gcd 1 with 32 banks)
  __shared__ int base_s[NC];
  const int t = threadIdx.x;

  // reset cross-kernel state
  for (int i = t; i < NC * MAXCH; i += 256) flags[i] = 0;
  if (t < NC) { fail_pos[t] = IMAX; nproto_g[t] = 0; }
  if (t == 0) out[0] = 0.f;

  // coalesced label load into LDS
  const int4* lp = (const int4*)labels;
  for (int i = t; i < (B >> 2); i += 256) {
    int4 v = lp[i];
    lab[i*4+0] = v.x; lab[i*4+1] = v.y; lab[i*4+2] = v.z; lab[i*4+3] = v.w;
  }
  for (int i = (B & ~3) + t; i < B; i += 256) lab[i] = labels[i];
  __syncthreads();

  const int segsz = (B + 255) >> 8;
  const int s0 = t * segsz, s1 = min(s0 + segsz, B);

  int loc[NC];
#pragma unroll
  for (int c = 0; c < NC; ++c) loc[c] = 0;
  for (int i = s0; i < s1; ++i) {
    int l = lab[i];
#pragma unroll
    for (int c = 0; c < NC; ++c) loc[c] += (l == c) ? 1 : 0;
  }
#pragma unroll
  for (int c = 0; c < NC; ++c) cnts[t][c] = loc[c];
  __syncthreads();

  // inclusive Hillis-Steele scan across 256 threads (vector of NC)
#pragma unroll
  for (int s = 1; s < 256; s <<= 1) {
    int v[NC];
#pragma unroll
    for (int c = 0; c < NC; ++c) v[c] = (t >= s) ? cnts[t - s][c] : 0;
    __syncthreads();
#pragma unroll
    for (int c = 0; c < NC; ++c) cnts[t][c] += v[c];
    __syncthreads();
  }

  if (t == 0) {
    int b = 0;
    for (int c = 0; c < NC; ++c) {
      int tc = cnts[255][c];
      base_s[c] = b;
      cls_base[c] = b; cls_cnt[c] = tc;
      b += tc;
    }
  }
  __syncthreads();

  int pos[NC];
#pragma unroll
  for (int c = 0; c < NC; ++c) pos[c] = base_s[c] + cnts[t][c] - loc[c];
  for (int i = s0; i < s1; ++i) {
    int l = lab[i];
#pragma unroll
    for (int c = 0; c < NC; ++c)
      if (l == c) order[pos[c]++] = i;
  }
}

// ---------------------------------------------------------------------------
// B: fused chunk-sum + decoupled-lookback prefix + verify + finalize.
// One wave per 32-sample chunk. All 2560 single-wave blocks are co-resident
// (10 waves/CU) and dispatched in order -> lookback spin is deadlock-free.
// ---------------------------------------------------------------------------
__global__ __launch_bounds__(64)
void sumverify_kernel(const float* __restrict__ feats, const int* __restrict__ order,
                      const int* __restrict__ cls_base, const int* __restrict__ cls_cnt,
                      float* __restrict__ chunksum, int* __restrict__ flags,
                      int* __restrict__ fail_pos,
                      float* __restrict__ gproto, float* __restrict__ p2s,
                      float* __restrict__ sps, int* __restrict__ nproto_g)
{
  const int c = blockIdx.x / MAXCH, g = blockIdx.x % MAXCH;
  const int cnt = cls_cnt[c];
  const int nch = (cnt + CH - 1) / CH;
  if (g >= nch) return;
  const int base = cls_base[c], lane = threadIdx.x;
  const int k0 = g * CH, k1 = min(k0 + CH, cnt);
  int myidx = (lane < CH && k0 + lane < cnt) ? order[base + k0 + lane] : 0;

  // ---- phase 1: chunk sum (4-deep load pipeline) ----
  float S[8] = {0, 0, 0, 0, 0, 0, 0, 0};
  {
    int k = k0;
    for (; k + 4 <= k1; k += 4) {
      float4 A[4], Bv[4];
#pragma unroll
      for (int j = 0; j < 4; ++j) {
        int idx = __shfl(myidx, k + j - k0, 64);
        const float4* fp = (const float4*)(feats + (size_t)idx * ND + lane * 8);
        A[j] = fp[0]; Bv[j] = fp[1];
      }
#pragma unroll
      for (int j = 0; j < 4; ++j) {
        S[0]+=A[j].x; S[1]+=A[j].y; S[2]+=A[j].z; S[3]+=A[j].w;
        S[4]+=Bv[j].x; S[5]+=Bv[j].y; S[6]+=Bv[j].z; S[7]+=Bv[j].w;
      }
    }
    for (; k < k1; ++k) {
      int idx = __shfl(myidx, k - k0, 64);
      const float4* fp = (const float4*)(feats + (size_t)idx * ND + lane * 8);
      float4 a = fp[0], b = fp[1];
      S[0]+=a.x; S[1]+=a.y; S[2]+=a.z; S[3]+=a.w;
      S[4]+=b.x; S[5]+=b.y; S[6]+=b.z; S[7]+=b.w;
    }
  }
  float4* cp = (float4*)(chunksum + ((size_t)c * MAXCH + g) * ND + lane * 8);
  cp[0] = make_float4(S[0], S[1], S[2], S[3]);
  cp[1] = make_float4(S[4], S[5], S[6], S[7]);
  __threadfence();
  if (lane == 0)
    __hip_atomic_store(&flags[c * MAXCH + g], 1, __ATOMIC_RELEASE, __HIP_MEMORY_SCOPE_AGENT);

  // ---- lookback: wait for predecessors, accumulate prefix ----
  for (int j = lane; j < g; j += 64)
    while (__hip_atomic_load(&flags[c * MAXCH + j], __ATOMIC_ACQUIRE,
                             __HIP_MEMORY_SCOPE_AGENT) == 0) { }
  __threadfence();

  float P[8] = {0, 0, 0, 0, 0, 0, 0, 0};
  {
    const float* cbase = chunksum + (size_t)c * MAXCH * ND + lane * 8;
    int j = 0;
    for (; j + 4 <= g; j += 4) {
      float4 A[4], Bv[4];
#pragma unroll
      for (int q = 0; q < 4; ++q) {
        const float4* pp = (const float4*)(cbase + (size_t)(j + q) * ND);
        A[q] = pp[0]; Bv[q] = pp[1];
      }
#pragma unroll
      for (int q = 0; q < 4; ++q) {
        P[0]+=A[q].x; P[1]+=A[q].y; P[2]+=A[q].z; P[3]+=A[q].w;
        P[4]+=Bv[q].x; P[5]+=Bv[q].y; P[6]+=Bv[q].z; P[7]+=Bv[q].w;
      }
    }
    for (; j < g; ++j) {
      const float4* pp = (const float4*)(cbase + (size_t)j * ND);
      float4 a = pp[0], b = pp[1];
      P[0]+=a.x; P[1]+=a.y; P[2]+=a.z; P[3]+=a.w;
      P[4]+=b.x; P[5]+=b.y; P[6]+=b.z; P[7]+=b.w;
    }
  }

  // ---- phase 2: verify (samples now L2-hot); walk running sum from prefix ----
  {
    int k = k0;
    for (; k + 4 <= k1; k += 4) {
      float4 A[4], Bv[4];
#pragma unroll
      for (int j = 0; j < 4; ++j) {
        int idx = __shfl(myidx, k + j - k0, 64);
        const float4* fp = (const float4*)(feats + (size_t)idx * ND + lane * 8);
        A[j] = fp[0]; Bv[j] = fp[1];
      }
#pragma unroll
      for (int j = 0; j < 4; ++j) {
        int kk = k + j;
        float f[8] = {A[j].x, A[j].y, A[j].z, A[j].w, Bv[j].x, Bv[j].y, Bv[j].z, Bv[j].w};
        if (kk > 0) {
          float inv = 1.f / (float)kk;
          float part = 0.f;
#pragma unroll
          for (int e = 0; e < 8; ++e) { float d = f[e] - P[e] * inv + FEPS; part += d * d; }
          float d2 = allred64(part);
          if (!(d2 < THR2) && lane == 0) atomicMin(&fail_pos[c], kk);
        }
#pragma unroll
        for (int e = 0; e < 8; ++e) P[e] += f[e];
      }
    }
    for (; k < k1; ++k) {
      int idx = __shfl(myidx, k - k0, 64);
      const float4* fp = (const float4*)(feats + (size_t)idx * ND + lane * 8);
      float4 fa = fp[0], fb = fp[1];
      float f[8] = {fa.x, fa.y, fa.z, fa.w, fb.x, fb.y, fb.z, fb.w};
      if (k > 0) {
        float inv = 1.f / (float)k;
        float part = 0.f;
#pragma unroll
        for (int e = 0; e < 8; ++e) { float d = f[e] - P[e] * inv + FEPS; part += d * d; }
        float d2 = allred64(part);
        if (!(d2 < THR2) && lane == 0) atomicMin(&fail_pos[c], k);
      }
#pragma unroll
      for (int e = 0; e < 8; ++e) P[e] += f[e];
    }
  }

  // ---- finalize: last chunk owns the class total (P == full-class sum) ----
  if (g == nch - 1) {
    float inv = 1.f / (float)cnt;
    float p[8];
#pragma unroll
    for (int e = 0; e < 8; ++e) p[e] = P[e] * inv;
    float4* gp = (float4*)(gproto + (size_t)c * NP * ND + lane * 8);
    gp[0] = make_float4(p[0], p[1], p[2], p[3]);
    gp[1] = make_float4(p[4], p[5], p[6], p[7]);
    float P2p = 0.f, SPp = 0.f;
#pragma unroll
    for (int e = 0; e < 8; ++e) { P2p += p[e]*p[e]; SPp += p[e]; }
    float P2 = allred64(P2p), SP = allred64(SPp);
    if (lane == 0) { p2s[c*NP] = P2; sps[c*NP] = SP; nproto_g[c] = 1; }
  }
}

// ---------------------------------------------------------------------------
// C: faithful sequential fallback — only for classes where speculation failed.
// ---------------------------------------------------------------------------
__global__ __launch_bounds__(64)
void fallback_kernel(const float* __restrict__ feats, const int* __restrict__ order,
                     const int* __restrict__ cls_base, const int* __restrict__ cls_cnt,
                     const int* __restrict__ fail_pos,
                     float* __restrict__ gproto, float* __restrict__ p2s,
                     float* __restrict__ sps, int* __restrict__ nproto_g)
{
  const int c = blockIdx.x;
  if (fail_pos[c] == IMAX) return;

  __shared__ float ls_proto[NLDS][ND];
  __shared__ int   ls_cnt[NP];
  const int lane = threadIdx.x;
  const int base = cls_base[c], cnt = cls_cnt[c];

  float p0[8];
  int cnt0 = 0, n = 0;
  float fA[8], fB[8], fC[8];

  auto LOADF = [&](float (&buf)[8], int m) {
    int idx = order[base + m];
    const float4* fp = (const float4*)(feats + (size_t)idx * ND + lane * 8);
    float4 a = fp[0], b = fp[1];
    buf[0]=a.x; buf[1]=a.y; buf[2]=a.z; buf[3]=a.w;
    buf[4]=b.x; buf[5]=b.y; buf[6]=b.z; buf[7]=b.w;
  };

  auto STEP = [&](float (&f)[8]) {
    float best = 3.4e38f;
    int bidx = 0;
    if (n > 0) {
      float part = 0.f;
#pragma unroll
      for (int e = 0; e < 8; ++e) { float d = f[e] - p0[e] + FEPS; part += d * d; }
      best = allred64(part);
      for (int j = 1; j < n; ++j) {
        float pj[8];
        if (j <= NLDS) {
          const float4* pp = (const float4*)(&ls_proto[j-1][lane*8]);
          float4 a = pp[0], b = pp[1];
          pj[0]=a.x; pj[1]=a.y; pj[2]=a.z; pj[3]=a.w;
          pj[4]=b.x; pj[5]=b.y; pj[6]=b.z; pj[7]=b.w;
        } else {
          const float4* pp = (const float4*)(gproto + ((size_t)c*NP + j)*ND + lane*8);
          float4 a = pp[0], b = pp[1];
          pj[0]=a.x; pj[1]=a.y; pj[2]=a.z; pj[3]=a.w;
          pj[4]=b.x; pj[5]=b.y; pj[6]=b.z; pj[7]=b.w;
        }
        float part2 = 0.f;
#pragma unroll
        for (int e = 0; e < 8; ++e) { float d = f[e] - pj[e] + FEPS; part2 += d * d; }
        float tot = allred64(part2);
        if (tot < best) { best = tot; bidx = j; }
      }
    }
    if (n > 0 && best < THR2) {
      if (bidx == 0) {
        float cc = (float)cnt0, inv = 1.f / (cc + 1.f);
#pragma unroll
        for (int e = 0; e < 8; ++e) p0[e] = (p0[e]*cc + f[e]) * inv;
        cnt0++;
      } else {
        int ci = ls_cnt[bidx];
        float cc = (float)ci, inv = 1.f / (cc + 1.f);
        if (bidx <= NLDS) {
          float* row = &ls_proto[bidx-1][lane*8];
#pragma unroll
          for (int e = 0; e < 8; ++e) row[e] = (row[e]*cc + f[e]) * inv;
        } else {
          float* row = gproto + ((size_t)c*NP + bidx)*ND + lane*8;
#pragma unroll
          for (int e = 0; e < 8; ++e) row[e] = (row[e]*cc + f[e]) * inv;
        }
        if (lane == 0) ls_cnt[bidx] = ci + 1;
      }
    } else {
      int app = min(n, NP - 1);
      if (app == 0) {
#pragma unroll
        for (int e = 0; e < 8; ++e) p0[e] = f[e];
        cnt0 = 1;
      } else if (app <= NLDS) {
        float* row = &ls_proto[app-1][lane*8];
#pragma unroll
        for (int e = 0; e < 8; ++e) row[e] = f[e];
        if (lane == 0) ls_cnt[app] = 1;
      } else {
        float* row = gproto + ((size_t)c*NP + app)*ND + lane*8;
#pragma unroll
        for (int e = 0; e < 8; ++e) row[e] = f[e];
        if (lane == 0) ls_cnt[app] = 1;
      }
      n = min(n + 1, NP);
    }
  };

  if (cnt > 0) LOADF(fA, 0);
  if (cnt > 1) LOADF(fB, 1);
  if (cnt > 2) LOADF(fC, 2);
  int m = 0;
  while (m < cnt) {
    STEP(fA); ++m; if (m + 2 < cnt) LOADF(fA, m + 2);
    if (m >= cnt) break;
    STEP(fB); ++m; if (m + 2 < cnt) LOADF(fB, m + 2);
    if (m >= cnt) break;
    STEP(fC); ++m; if (m + 2 < cnt) LOADF(fC, m + 2);
  }

  for (int j = 0; j < n; ++j) {
    float pj[8];
    if (j == 0) {
#pragma unroll
      for (int e = 0; e < 8; ++e) pj[e] = p0[e];
    } else if (j <= NLDS) {
      const float4* pp = (const float4*)(&ls_proto[j-1][lane*8]);
      float4 a = pp[0], b = pp[1];
      pj[0]=a.x; pj[1]=a.y; pj[2]=a.z; pj[3]=a.w;
      pj[4]=b.x; pj[5]=b.y; pj[6]=b.z; pj[7]=b.w;
    } else {
      const float4* pp = (const float4*)(gproto + ((size_t)c*NP + j)*ND + lane*8);
      float4 a = pp[0], b = pp[1];
      pj[0]=a.x; pj[1]=a.y; pj[2]=a.z; pj[3]=a.w;
      pj[4]=b.x; pj[5]=b.y; pj[6]=b.z; pj[7]=b.w;
    }
    float4* gp = (float4*)(gproto + ((size_t)c*NP + j)*ND + lane*8);
    gp[0] = make_float4(pj[0], pj[1], pj[2], pj[3]);
    gp[1] = make_float4(pj[4], pj[5], pj[6], pj[7]);
    float P2p = 0.f, SPp = 0.f;
#pragma unroll
    for (int e = 0; e < 8; ++e) { P2p += pj[e]*pj[e]; SPp += pj[e]; }
    float P2 = allred64(P2p), SP = allred64(SPp);
    if (lane == 0) { p2s[c*NP + j] = P2; sps[c*NP + j] = SP; }
  }
  if (lane == 0) nproto_g[c] = n;
}

// ---------------------------------------------------------------------------
// D: loss. One wave per sample; masked terms exact.
// ---------------------------------------------------------------------------
__global__ __launch_bounds__(256)
void loss_kernel(const float* __restrict__ feats, const int* __restrict__ labels, int B,
                 const float* __restrict__ gproto, const float* __restrict__ p2s,
                 const float* __restrict__ sps, const int* __restrict__ nproto_g,
                 float* __restrict__ out)
{
  __shared__ float bsum[4];
  const int lane = threadIdx.x & 63;
  const int wid  = threadIdx.x >> 6;
  const int gw   = blockIdx.x * 4 + wid;
  const int nw   = gridDim.x * 4;

  int np[NC];
#pragma unroll
  for (int cc = 0; cc < NC; ++cc) np[cc] = nproto_g[cc];

  float acc = 0.f;
  for (int b = gw; b < B; b += nw) {
    const float4* fp = (const float4*)(feats + (size_t)b * ND + lane * 8);
    float4 a4 = fp[0], b4 = fp[1];
    float f[8] = {a4.x, a4.y, a4.z, a4.w, b4.x, b4.y, b4.z, b4.w};
    float f2p = 0.f, sfp = 0.f;
#pragma unroll
    for (int e = 0; e < 8; ++e) { f2p += f[e]*f[e]; sfp += f[e]; }
    float f2 = allred64(f2p);
    float sf = allred64(sfp);
    int lab = labels[b];

    float one = 0.f, num = 0.f, pw = 0.f;
    for (int cc = 0; cc < NC; ++cc) {
      int nn = np[cc];
      if (nn <= 0) continue;
      float sume = 0.f, bestd2 = 3.4e38f;
      for (int j = 0; j < nn; ++j) {
        const float4* pp = (const float4*)(gproto + ((size_t)cc*NP + j)*ND + lane*8);
        float4 pa = pp[0], pb = pp[1];
        float dp = f[0]*pa.x + f[1]*pa.y + f[2]*pa.z + f[3]*pa.w
                 + f[4]*pb.x + f[5]*pb.y + f[6]*pb.z + f[7]*pb.w;
        float dot = allred64(dp);
        float d2 = f2 + p2s[cc*NP + j] - 2.f*dot
                 + 2.f*FEPS*(sf - sps[cc*NP + j]) + (float)ND*FEPS*FEPS;
        d2 = fmaxf(d2, 0.f);
        sume  += expf(-GAMMA * d2);
        bestd2 = fminf(bestd2, d2);
      }
      one += sume;
      if (cc == lab) num = sume;
      float dmin = sqrtf(bestd2);
      float sign = (cc == lab) ? 1.f : -1.f;
      float z = BCONST - (TAO - dmin) * sign;
      float g = (z > 10.f) ? z : log1pf(expf(z));
      pw += g;
    }
    float prob = 1e-6f + ((one > 0.f) ? num / one : one);
    acc += -logf(prob) + LAMBDA * pw;
  }

  if (lane == 0) bsum[wid] = acc;
  __syncthreads();
  if (threadIdx.x == 0) atomicAdd(out, bsum[0] + bsum[1] + bsum[2] + bsum[3]);
}

// ---------------------------------------------------------------------------
extern "C" void kernel_launch(void* const* d_in, const int* in_sizes, int n_in,
                              void* d_out, int out_size, void* d_ws, size_t ws_size,
                              hipStream_t stream) {
  const float* feats  = (const float*)d_in[0];
  const int*   labels = (const int*)d_in[1];
  int B = in_sizes[0] / ND;   // 8192

  float* gproto   = (float*)d_ws;                        // NC*NP*ND
  float* p2s      = gproto + (size_t)NC * NP * ND;       // NC*NP
  float* sps      = p2s + NC * NP;                       // NC*NP
  float* chunksum = sps + NC * NP;                       // NC*MAXCH*ND
  int*   nproto_g = (int*)(chunksum + (size_t)NC * MAXCH * ND); // NC
  int*   order    = nproto_g + NC;                       // B
  int*   cls_base = order + B;                           // NC
  int*   cls_cnt  = cls_base + NC;                       // NC
  int*   fail_pos = cls_cnt + NC;                        // NC
  int*   flags    = fail_pos + NC;                       // NC*MAXCH

  hipLaunchKernelGGL(ord_kernel, dim3(1), dim3(256), 0, stream,
                     labels, B, order, cls_base, cls_cnt, fail_pos, flags,
                     nproto_g, (float*)d_out);
  hipLaunchKernelGGL(sumverify_kernel, dim3(NC * MAXCH), dim3(64), 0, stream,
                     feats, order, cls_base, cls_cnt, chunksum, flags,
                     fail_pos, gproto, p2s, sps, nproto_g);
  hipLaunchKernelGGL(fallback_kernel, dim3(NC), dim3(64), 0, stream,
                     feats, order, cls_base, cls_cnt, fail_pos,
                     gproto, p2s, sps, nproto_g);
  hipLaunchKernelGGL(loss_kernel, dim3(2048), dim3(256), 0, stream,
                     feats, labels, B, gproto, p2s, sps, nproto_g, (float*)d_out);
}

// Round 5
// 88.823 us; speedup vs baseline: 1.2983x; 1.2983x over previous
//
#include <hip/hip_runtime.h>
#include <math.h>

#define NC 10
#define NP 128
#define ND 512
#define GAMMA  0.1f
#define BCONST 10.0f
#define TAO    1.0f
#define LAMBDA 0.1f
#define THR2   1600.0f     // THRESHOLD^2 (compare d2 instead of sqrt(d2))
#define FEPS   1e-6f
#define NLDS   12          // fallback: proto slots 1..NLDS in LDS; slot 0 in regs; rest global
#define CH     16          // speculation chunk size
#define MAXCH  512         // max chunks per class (covers all-8192-in-one-class)
#define IMAX   0x7FFFFFFF

__device__ __forceinline__ float allred64(float v) {
#pragma unroll
  for (int m = 1; m < 64; m <<= 1) v += __shfl_xor(v, m, 64);
  return v;
}

// ---------------------------------------------------------------------------
// A: stable per-class compaction. One block, 256 threads, wave-level scans
// (2 barriers). Also resets fail_pos/nproto/d_out.
// ---------------------------------------------------------------------------
__global__ __launch_bounds__(256)
void ord_kernel(const int* __restrict__ labels, int B,
                int* __restrict__ order, int* __restrict__ cls_base,
                int* __restrict__ cls_cnt, int* __restrict__ fail_pos,
                int* __restrict__ nproto_g, float* __restrict__ out)
{
  __shared__ int lab[8192];
  __shared__ int wtot[4][NC];
  const int t = threadIdx.x, lane = t & 63, w = t >> 6;

  if (t < NC) { fail_pos[t] = IMAX; nproto_g[t] = 0; }
  if (t == 0) out[0] = 0.f;

  // coalesced label load into LDS
  const int4* lp = (const int4*)labels;
  for (int i = t; i < (B >> 2); i += 256) {
    int4 v = lp[i];
    lab[i*4+0] = v.x; lab[i*4+1] = v.y; lab[i*4+2] = v.z; lab[i*4+3] = v.w;
  }
  for (int i = (B & ~3) + t; i < B; i += 256) lab[i] = labels[i];
  __syncthreads();

  const int segsz = (B + 255) >> 8;
  const int s0 = t * segsz, s1 = min(s0 + segsz, B);

  int loc[NC];
#pragma unroll
  for (int c = 0; c < NC; ++c) loc[c] = 0;
  for (int i = s0; i < s1; ++i) {
    int l = lab[i];
#pragma unroll
    for (int c = 0; c < NC; ++c) loc[c] += (l == c) ? 1 : 0;
  }

  // per-wave inclusive scan, per class (independent shuffle chains)
  int pre[NC];
#pragma unroll
  for (int c = 0; c < NC; ++c) pre[c] = loc[c];
#pragma unroll
  for (int m = 1; m < 64; m <<= 1) {
#pragma unroll
    for (int c = 0; c < NC; ++c) {
      int u = __shfl_up(pre[c], m, 64);
      if (lane >= m) pre[c] += u;
    }
  }
  if (lane == 63) {
#pragma unroll
    for (int c = 0; c < NC; ++c) wtot[w][c] = pre[c];
  }
  __syncthreads();

  // global base per thread per class
  int pos[NC];
  {
    int cb = 0;
#pragma unroll
    for (int c = 0; c < NC; ++c) {
      int tot = wtot[0][c] + wtot[1][c] + wtot[2][c] + wtot[3][c];
      int before = 0;
#pragma unroll
      for (int ww = 0; ww < 4; ++ww) before += (ww < w) ? wtot[ww][c] : 0;
      pos[c] = cb + before + (pre[c] - loc[c]);
      if (t == 0) { cls_base[c] = cb; cls_cnt[c] = tot; }
      cb += tot;
    }
  }

  // stable scatter (contiguous segments preserve order)
  for (int i = s0; i < s1; ++i) {
    int l = lab[i];
#pragma unroll
    for (int c = 0; c < NC; ++c)
      if (l == c) order[pos[c]++] = i;
  }
}

// ---------------------------------------------------------------------------
// B: per-chunk feature sums. One wave per 16-sample chunk; 4-deep pipeline.
// ---------------------------------------------------------------------------
__global__ __launch_bounds__(64)
void chunksum_kernel(const float* __restrict__ feats, const int* __restrict__ order,
                     const int* __restrict__ cls_base, const int* __restrict__ cls_cnt,
                     float* __restrict__ chunksum)
{
  const int c = blockIdx.x / MAXCH, g = blockIdx.x % MAXCH;
  const int cnt = cls_cnt[c];
  const int nch = (cnt + CH - 1) / CH;
  if (g >= nch) return;
  const int base = cls_base[c], lane = threadIdx.x;
  const int k0 = g * CH, k1 = min(k0 + CH, cnt);
  int myidx = (lane < CH && k0 + lane < cnt) ? order[base + k0 + lane] : 0;

  float S[8] = {0, 0, 0, 0, 0, 0, 0, 0};
  int k = k0;
  for (; k + 4 <= k1; k += 4) {
    float4 A[4], Bv[4];
#pragma unroll
    for (int j = 0; j < 4; ++j) {
      int idx = __shfl(myidx, k + j - k0, 64);
      const float4* fp = (const float4*)(feats + (size_t)idx * ND + lane * 8);
      A[j] = fp[0]; Bv[j] = fp[1];
    }
#pragma unroll
    for (int j = 0; j < 4; ++j) {
      S[0]+=A[j].x; S[1]+=A[j].y; S[2]+=A[j].z; S[3]+=A[j].w;
      S[4]+=Bv[j].x; S[5]+=Bv[j].y; S[6]+=Bv[j].z; S[7]+=Bv[j].w;
    }
  }
  for (; k < k1; ++k) {
    int idx = __shfl(myidx, k - k0, 64);
    const float4* fp = (const float4*)(feats + (size_t)idx * ND + lane * 8);
    float4 a = fp[0], b = fp[1];
    S[0]+=a.x; S[1]+=a.y; S[2]+=a.z; S[3]+=a.w;
    S[4]+=b.x; S[5]+=b.y; S[6]+=b.z; S[7]+=b.w;
  }
  float4* cp = (float4*)(chunksum + ((size_t)c * MAXCH + g) * ND + lane * 8);
  cp[0] = make_float4(S[0], S[1], S[2], S[3]);
  cp[1] = make_float4(S[4], S[5], S[6], S[7]);
}

// ---------------------------------------------------------------------------
// C: verify. Each block self-computes its prefix from raw predecessor chunk
// sums (launch boundary guarantees completion; no spin/fence). Batched
// 4-sample butterflies. Last chunk finalizes the speculative prototype.
// ---------------------------------------------------------------------------
__global__ __launch_bounds__(64)
void verify_kernel(const float* __restrict__ feats, const int* __restrict__ order,
                   const int* __restrict__ cls_base, const int* __restrict__ cls_cnt,
                   const float* __restrict__ chunksum, int* __restrict__ fail_pos,
                   float* __restrict__ gproto, float* __restrict__ p2s,
                   float* __restrict__ sps, int* __restrict__ nproto_g)
{
  const int c = blockIdx.x / MAXCH, g = blockIdx.x % MAXCH;
  const int cnt = cls_cnt[c];
  const int nch = (cnt + CH - 1) / CH;
  if (g >= nch) return;
  const int base = cls_base[c], lane = threadIdx.x;
  const int k0 = g * CH, k1 = min(k0 + CH, cnt);
  int myidx = (lane < CH && k0 + lane < cnt) ? order[base + k0 + lane] : 0;

  // ---- prefix over predecessor chunk sums (ascending, 4-deep) ----
  float P[8] = {0, 0, 0, 0, 0, 0, 0, 0};
  {
    const float* cbase = chunksum + (size_t)c * MAXCH * ND + lane * 8;
    int j = 0;
    for (; j + 4 <= g; j += 4) {
      float4 A[4], Bv[4];
#pragma unroll
      for (int q = 0; q < 4; ++q) {
        const float4* pp = (const float4*)(cbase + (size_t)(j + q) * ND);
        A[q] = pp[0]; Bv[q] = pp[1];
      }
#pragma unroll
      for (int q = 0; q < 4; ++q) {
        P[0]+=A[q].x; P[1]+=A[q].y; P[2]+=A[q].z; P[3]+=A[q].w;
        P[4]+=Bv[q].x; P[5]+=Bv[q].y; P[6]+=Bv[q].z; P[7]+=Bv[q].w;
      }
    }
    for (; j < g; ++j) {
      const float4* pp = (const float4*)(cbase + (size_t)j * ND);
      float4 a = pp[0], b = pp[1];
      P[0]+=a.x; P[1]+=a.y; P[2]+=a.z; P[3]+=a.w;
      P[4]+=b.x; P[5]+=b.y; P[6]+=b.z; P[7]+=b.w;
    }
  }

  // ---- verify 16 samples, 4 per batched butterfly ----
  int k = k0;
  for (; k + 4 <= k1; k += 4) {
    float4 A[4], Bv[4];
#pragma unroll
    for (int j = 0; j < 4; ++j) {
      int idx = __shfl(myidx, k + j - k0, 64);
      const float4* fp = (const float4*)(feats + (size_t)idx * ND + lane * 8);
      A[j] = fp[0]; Bv[j] = fp[1];
    }
    float part[4];
#pragma unroll
    for (int j = 0; j < 4; ++j) {
      int kk = k + j;
      float f[8] = {A[j].x, A[j].y, A[j].z, A[j].w, Bv[j].x, Bv[j].y, Bv[j].z, Bv[j].w};
      if (kk > 0) {
        float inv = 1.f / (float)kk;
        float p = 0.f;
#pragma unroll
        for (int e = 0; e < 8; ++e) { float d = f[e] - P[e] * inv + FEPS; p += d * d; }
        part[j] = p;
      } else part[j] = 0.f;
#pragma unroll
      for (int e = 0; e < 8; ++e) P[e] += f[e];
    }
#pragma unroll
    for (int m = 1; m < 64; m <<= 1) {
#pragma unroll
      for (int j = 0; j < 4; ++j) part[j] += __shfl_xor(part[j], m, 64);
    }
    if (lane == 0) {
#pragma unroll
      for (int j = 0; j < 4; ++j) {
        int kk = k + j;
        if (kk > 0 && !(part[j] < THR2)) atomicMin(&fail_pos[c], kk);
      }
    }
  }
  for (; k < k1; ++k) {
    int idx = __shfl(myidx, k - k0, 64);
    const float4* fp = (const float4*)(feats + (size_t)idx * ND + lane * 8);
    float4 fa = fp[0], fb = fp[1];
    float f[8] = {fa.x, fa.y, fa.z, fa.w, fb.x, fb.y, fb.z, fb.w};
    if (k > 0) {
      float inv = 1.f / (float)k;
      float p = 0.f;
#pragma unroll
      for (int e = 0; e < 8; ++e) { float d = f[e] - P[e] * inv + FEPS; p += d * d; }
      float d2 = allred64(p);
      if (!(d2 < THR2) && lane == 0) atomicMin(&fail_pos[c], k);
    }
#pragma unroll
    for (int e = 0; e < 8; ++e) P[e] += f[e];
  }

  // ---- last chunk owns the full class sum: speculative finalize ----
  if (g == nch - 1) {
    float inv = 1.f / (float)cnt;
    float p[8];
#pragma unroll
    for (int e = 0; e < 8; ++e) p[e] = P[e] * inv;
    float4* gp = (float4*)(gproto + (size_t)c * NP * ND + lane * 8);
    gp[0] = make_float4(p[0], p[1], p[2], p[3]);
    gp[1] = make_float4(p[4], p[5], p[6], p[7]);
    float P2p = 0.f, SPp = 0.f;
#pragma unroll
    for (int e = 0; e < 8; ++e) { P2p += p[e]*p[e]; SPp += p[e]; }
    float P2 = allred64(P2p), SP = allred64(SPp);
    if (lane == 0) { p2s[c*NP] = P2; sps[c*NP] = SP; nproto_g[c] = 1; }
  }
}

// ---------------------------------------------------------------------------
// D: faithful sequential fallback — only for classes where speculation failed.
// ---------------------------------------------------------------------------
__global__ __launch_bounds__(64)
void fallback_kernel(const float* __restrict__ feats, const int* __restrict__ order,
                     const int* __restrict__ cls_base, const int* __restrict__ cls_cnt,
                     const int* __restrict__ fail_pos,
                     float* __restrict__ gproto, float* __restrict__ p2s,
                     float* __restrict__ sps, int* __restrict__ nproto_g)
{
  const int c = blockIdx.x;
  if (fail_pos[c] == IMAX) return;

  __shared__ float ls_proto[NLDS][ND];
  __shared__ int   ls_cnt[NP];
  const int lane = threadIdx.x;
  const int base = cls_base[c], cnt = cls_cnt[c];

  float p0[8];
  int cnt0 = 0, n = 0;
  float fA[8], fB[8], fC[8];

  auto LOADF = [&](float (&buf)[8], int m) {
    int idx = order[base + m];
    const float4* fp = (const float4*)(feats + (size_t)idx * ND + lane * 8);
    float4 a = fp[0], b = fp[1];
    buf[0]=a.x; buf[1]=a.y; buf[2]=a.z; buf[3]=a.w;
    buf[4]=b.x; buf[5]=b.y; buf[6]=b.z; buf[7]=b.w;
  };

  auto STEP = [&](float (&f)[8]) {
    float best = 3.4e38f;
    int bidx = 0;
    if (n > 0) {
      float part = 0.f;
#pragma unroll
      for (int e = 0; e < 8; ++e) { float d = f[e] - p0[e] + FEPS; part += d * d; }
      best = allred64(part);
      for (int j = 1; j < n; ++j) {
        float pj[8];
        if (j <= NLDS) {
          const float4* pp = (const float4*)(&ls_proto[j-1][lane*8]);
          float4 a = pp[0], b = pp[1];
          pj[0]=a.x; pj[1]=a.y; pj[2]=a.z; pj[3]=a.w;
          pj[4]=b.x; pj[5]=b.y; pj[6]=b.z; pj[7]=b.w;
        } else {
          const float4* pp = (const float4*)(gproto + ((size_t)c*NP + j)*ND + lane*8);
          float4 a = pp[0], b = pp[1];
          pj[0]=a.x; pj[1]=a.y; pj[2]=a.z; pj[3]=a.w;
          pj[4]=b.x; pj[5]=b.y; pj[6]=b.z; pj[7]=b.w;
        }
        float part2 = 0.f;
#pragma unroll
        for (int e = 0; e < 8; ++e) { float d = f[e] - pj[e] + FEPS; part2 += d * d; }
        float tot = allred64(part2);
        if (tot < best) { best = tot; bidx = j; }
      }
    }
    if (n > 0 && best < THR2) {
      if (bidx == 0) {
        float cc = (float)cnt0, inv = 1.f / (cc + 1.f);
#pragma unroll
        for (int e = 0; e < 8; ++e) p0[e] = (p0[e]*cc + f[e]) * inv;
        cnt0++;
      } else {
        int ci = ls_cnt[bidx];
        float cc = (float)ci, inv = 1.f / (cc + 1.f);
        if (bidx <= NLDS) {
          float* row = &ls_proto[bidx-1][lane*8];
#pragma unroll
          for (int e = 0; e < 8; ++e) row[e] = (row[e]*cc + f[e]) * inv;
        } else {
          float* row = gproto + ((size_t)c*NP + bidx)*ND + lane*8;
#pragma unroll
          for (int e = 0; e < 8; ++e) row[e] = (row[e]*cc + f[e]) * inv;
        }
        if (lane == 0) ls_cnt[bidx] = ci + 1;
      }
    } else {
      int app = min(n, NP - 1);
      if (app == 0) {
#pragma unroll
        for (int e = 0; e < 8; ++e) p0[e] = f[e];
        cnt0 = 1;
      } else if (app <= NLDS) {
        float* row = &ls_proto[app-1][lane*8];
#pragma unroll
        for (int e = 0; e < 8; ++e) row[e] = f[e];
        if (lane == 0) ls_cnt[app] = 1;
      } else {
        float* row = gproto + ((size_t)c*NP + app)*ND + lane*8;
#pragma unroll
        for (int e = 0; e < 8; ++e) row[e] = f[e];
        if (lane == 0) ls_cnt[app] = 1;
      }
      n = min(n + 1, NP);
    }
  };

  if (cnt > 0) LOADF(fA, 0);
  if (cnt > 1) LOADF(fB, 1);
  if (cnt > 2) LOADF(fC, 2);
  int m = 0;
  while (m < cnt) {
    STEP(fA); ++m; if (m + 2 < cnt) LOADF(fA, m + 2);
    if (m >= cnt) break;
    STEP(fB); ++m; if (m + 2 < cnt) LOADF(fB, m + 2);
    if (m >= cnt) break;
    STEP(fC); ++m; if (m + 2 < cnt) LOADF(fC, m + 2);
  }

  for (int j = 0; j < n; ++j) {
    float pj[8];
    if (j == 0) {
#pragma unroll
      for (int e = 0; e < 8; ++e) pj[e] = p0[e];
    } else if (j <= NLDS) {
      const float4* pp = (const float4*)(&ls_proto[j-1][lane*8]);
      float4 a = pp[0], b = pp[1];
      pj[0]=a.x; pj[1]=a.y; pj[2]=a.z; pj[3]=a.w;
      pj[4]=b.x; pj[5]=b.y; pj[6]=b.z; pj[7]=b.w;
    } else {
      const float4* pp = (const float4*)(gproto + ((size_t)c*NP + j)*ND + lane*8);
      float4 a = pp[0], b = pp[1];
      pj[0]=a.x; pj[1]=a.y; pj[2]=a.z; pj[3]=a.w;
      pj[4]=b.x; pj[5]=b.y; pj[6]=b.z; pj[7]=b.w;
    }
    float4* gp = (float4*)(gproto + ((size_t)c*NP + j)*ND + lane*8);
    gp[0] = make_float4(pj[0], pj[1], pj[2], pj[3]);
    gp[1] = make_float4(pj[4], pj[5], pj[6], pj[7]);
    float P2p = 0.f, SPp = 0.f;
#pragma unroll
    for (int e = 0; e < 8; ++e) { P2p += pj[e]*pj[e]; SPp += pj[e]; }
    float P2 = allred64(P2p), SP = allred64(SPp);
    if (lane == 0) { p2s[c*NP + j] = P2; sps[c*NP + j] = SP; }
  }
  if (lane == 0) nproto_g[c] = n;
}

// ---------------------------------------------------------------------------
// E: loss. One wave per sample. Fast path (all nproto==1): ONE batched
// 12-value butterfly per sample. General path retained for fallback data.
// ---------------------------------------------------------------------------
__global__ __launch_bounds__(256)
void loss_kernel(const float* __restrict__ feats, const int* __restrict__ labels, int B,
                 const float* __restrict__ gproto, const float* __restrict__ p2s,
                 const float* __restrict__ sps, const int* __restrict__ nproto_g,
                 float* __restrict__ out)
{
  __shared__ float bsum[4];
  const int lane = threadIdx.x & 63;
  const int wid  = threadIdx.x >> 6;
  const int gw   = blockIdx.x * 4 + wid;
  const int nw   = gridDim.x * 4;

  int np[NC];
  bool fast = true;
#pragma unroll
  for (int cc = 0; cc < NC; ++cc) { np[cc] = nproto_g[cc]; fast &= (np[cc] == 1); }

  float acc = 0.f;

  if (fast) {
    float p2v[NC], spv[NC];
#pragma unroll
    for (int cc = 0; cc < NC; ++cc) { p2v[cc] = p2s[cc*NP]; spv[cc] = sps[cc*NP]; }

    for (int b = gw; b < B; b += nw) {
      const float4* fp = (const float4*)(feats + (size_t)b * ND + lane * 8);
      float4 a4 = fp[0], b4 = fp[1];
      float f[8] = {a4.x, a4.y, a4.z, a4.w, b4.x, b4.y, b4.z, b4.w};
      int lab = labels[b];

      float v[12];
#pragma unroll
      for (int cc = 0; cc < NC; ++cc) {
        const float4* pp = (const float4*)(gproto + (size_t)cc * NP * ND + lane * 8);
        float4 pa = pp[0], pb = pp[1];
        v[cc] = f[0]*pa.x + f[1]*pa.y + f[2]*pa.z + f[3]*pa.w
              + f[4]*pb.x + f[5]*pb.y + f[6]*pb.z + f[7]*pb.w;
      }
      float f2p = 0.f, sfp = 0.f;
#pragma unroll
      for (int e = 0; e < 8; ++e) { f2p += f[e]*f[e]; sfp += f[e]; }
      v[10] = f2p; v[11] = sfp;

#pragma unroll
      for (int m = 1; m < 64; m <<= 1) {
#pragma unroll
        for (int q = 0; q < 12; ++q) v[q] += __shfl_xor(v[q], m, 64);
      }
      float f2 = v[10], sf = v[11];

      float one = 0.f, num = 0.f, pw = 0.f;
#pragma unroll
      for (int cc = 0; cc < NC; ++cc) {
        float d2 = f2 + p2v[cc] - 2.f*v[cc]
                 + 2.f*FEPS*(sf - spv[cc]) + (float)ND*FEPS*FEPS;
        d2 = fmaxf(d2, 0.f);
        float e = expf(-GAMMA * d2);
        one += e;
        if (cc == lab) num = e;
        float dmin = sqrtf(d2);
        float sign = (cc == lab) ? 1.f : -1.f;
        float z = BCONST - (TAO - dmin) * sign;
        float gg = (z > 10.f) ? z : log1pf(expf(z));
        pw += gg;
      }
      float prob = 1e-6f + ((one > 0.f) ? num / one : one);
      acc += -logf(prob) + LAMBDA * pw;
    }
  } else {
    for (int b = gw; b < B; b += nw) {
      const float4* fp = (const float4*)(feats + (size_t)b * ND + lane * 8);
      float4 a4 = fp[0], b4 = fp[1];
      float f[8] = {a4.x, a4.y, a4.z, a4.w, b4.x, b4.y, b4.z, b4.w};
      float f2p = 0.f, sfp = 0.f;
#pragma unroll
      for (int e = 0; e < 8; ++e) { f2p += f[e]*f[e]; sfp += f[e]; }
      float f2 = allred64(f2p);
      float sf = allred64(sfp);
      int lab = labels[b];

      float one = 0.f, num = 0.f, pw = 0.f;
      for (int cc = 0; cc < NC; ++cc) {
        int nn = np[cc];
        if (nn <= 0) continue;
        float sume = 0.f, bestd2 = 3.4e38f;
        for (int j = 0; j < nn; ++j) {
          const float4* pp = (const float4*)(gproto + ((size_t)cc*NP + j)*ND + lane*8);
          float4 pa = pp[0], pb = pp[1];
          float dp = f[0]*pa.x + f[1]*pa.y + f[2]*pa.z + f[3]*pa.w
                   + f[4]*pb.x + f[5]*pb.y + f[6]*pb.z + f[7]*pb.w;
          float dot = allred64(dp);
          float d2 = f2 + p2s[cc*NP + j] - 2.f*dot
                   + 2.f*FEPS*(sf - sps[cc*NP + j]) + (float)ND*FEPS*FEPS;
          d2 = fmaxf(d2, 0.f);
          sume  += expf(-GAMMA * d2);
          bestd2 = fminf(bestd2, d2);
        }
        one += sume;
        if (cc == lab) num = sume;
        float dmin = sqrtf(bestd2);
        float sign = (cc == lab) ? 1.f : -1.f;
        float z = BCONST - (TAO - dmin) * sign;
        float g = (z > 10.f) ? z : log1pf(expf(z));
        pw += g;
      }
      float prob = 1e-6f + ((one > 0.f) ? num / one : one);
      acc += -logf(prob) + LAMBDA * pw;
    }
  }

  if (lane == 0) bsum[wid] = acc;
  __syncthreads();
  if (threadIdx.x == 0) atomicAdd(out, bsum[0] + bsum[1] + bsum[2] + bsum[3]);
}

// ---------------------------------------------------------------------------
extern "C" void kernel_launch(void* const* d_in, const int* in_sizes, int n_in,
                              void* d_out, int out_size, void* d_ws, size_t ws_size,
                              hipStream_t stream) {
  const float* feats  = (const float*)d_in[0];
  const int*   labels = (const int*)d_in[1];
  int B = in_sizes[0] / ND;   // 8192

  float* gproto   = (float*)d_ws;                        // NC*NP*ND
  float* p2s      = gproto + (size_t)NC * NP * ND;       // NC*NP
  float* sps      = p2s + NC * NP;                       // NC*NP
  float* chunksum = sps + NC * NP;                       // NC*MAXCH*ND
  int*   nproto_g = (int*)(chunksum + (size_t)NC * MAXCH * ND); // NC
  int*   order    = nproto_g + NC;                       // B
  int*   cls_base = order + B;                           // NC
  int*   cls_cnt  = cls_base + NC;                       // NC
  int*   fail_pos = cls_cnt + NC;                        // NC

  hipLaunchKernelGGL(ord_kernel, dim3(1), dim3(256), 0, stream,
                     labels, B, order, cls_base, cls_cnt, fail_pos,
                     nproto_g, (float*)d_out);
  hipLaunchKernelGGL(chunksum_kernel, dim3(NC * MAXCH), dim3(64), 0, stream,
                     feats, order, cls_base, cls_cnt, chunksum);
  hipLaunchKernelGGL(verify_kernel, dim3(NC * MAXCH), dim3(64), 0, stream,
                     feats, order, cls_base, cls_cnt, chunksum, fail_pos,
                     gproto, p2s, sps, nproto_g);
  hipLaunchKernelGGL(fallback_kernel, dim3(NC), dim3(64), 0, stream,
                     feats, order, cls_base, cls_cnt, fail_pos,
                     gproto, p2s, sps, nproto_g);
  hipLaunchKernelGGL(loss_kernel, dim3(2048), dim3(256), 0, stream,
                     feats, labels, B, gproto, p2s, sps, nproto_g, (float*)d_out);
}